// Round 4
// baseline (245.264 us; speedup 1.0000x reference)
//
#include <hip/hip_runtime.h>
#include <cmath>

#define C_DIM   1024
#define H_DIM   16
#define HD      64
#define N_TOK   2048
#define M_TOK   4096
#define LOG2E   1.44269504088896340736f

typedef _Float16 f16;
typedef __attribute__((ext_vector_type(8))) _Float16 f16x8;
typedef __attribute__((ext_vector_type(4))) float    f32x4;

// async global->LDS, 16B per lane; LDS dest = wave-uniform base + lane*16
__device__ __forceinline__ void gl_lds16(const void* g, void* l) {
  __builtin_amdgcn_global_load_lds((const __attribute__((address_space(1))) void*)g,
                                   (__attribute__((address_space(3))) void*)l, 16, 0, 0);
}

// ---------------------------------------------------------------------------
// fp32 -> fp16 convert: x (4.19M), qkv_w (3.15M), proj_w (1.05M), float4/thread
// ---------------------------------------------------------------------------
#define CVT_X4 1048576
#define CVT_W4 786432
#define CVT_P4 262144
__global__ __launch_bounds__(256) void cvt_all(const float* __restrict__ x,
                                               const float* __restrict__ w1,
                                               const float* __restrict__ w2,
                                               f16* __restrict__ xh,
                                               f16* __restrict__ wh1,
                                               f16* __restrict__ wh2) {
  const int i = blockIdx.x * 256 + threadIdx.x;
  const float4* src; f16* dst; int off;
  if (i < CVT_X4)               { src = (const float4*)x;  dst = xh;  off = i; }
  else if (i < CVT_X4 + CVT_W4) { src = (const float4*)w1; dst = wh1; off = i - CVT_X4; }
  else                          { src = (const float4*)w2; dst = wh2; off = i - CVT_X4 - CVT_W4; }
  const float4 v = src[off];
  union { f16 h[4]; ushort4 u; } p;
  p.h[0] = (f16)v.x; p.h[1] = (f16)v.y; p.h[2] = (f16)v.z; p.h[3] = (f16)v.w;
  *(ushort4*)(dst + (size_t)off * 4) = p.u;
}

// ---------------------------------------------------------------------------
// Shared MFMA NT-GEMM mainloop: 128x128 tile, BK=32, 4 waves (2x2), fp16.
// ---------------------------------------------------------------------------
__device__ __forceinline__ void gemm_mainloop(const f16* __restrict__ A,
                                              const f16* __restrict__ B,
                                              int K, int bm, int bn,
                                              f16* As, f16* Bs,
                                              f32x4 (&acc)[4][4]) {
  const int tid  = threadIdx.x;
  const int w    = tid >> 6, lane = tid & 63;
  const int wm   = w >> 1,   wn   = w & 1;
  const int ln   = lane & 15, quad = lane >> 4;
  const int sr   = lane >> 2;
  const int sc   = (lane & 3) << 3;

  const f16* Ag0 = A + (size_t)(bm + w * 16 + sr) * K + sc;
  const f16* Ag1 = A + (size_t)(bm + (w + 4) * 16 + sr) * K + sc;
  const f16* Bg0 = B + (size_t)(bn + w * 16 + sr) * K + sc;
  const f16* Bg1 = B + (size_t)(bn + (w + 4) * 16 + sr) * K + sc;
  f16* Al0 = As + (w * 16) * 32;
  f16* Al1 = As + ((w + 4) * 16) * 32;
  f16* Bl0 = Bs + (w * 16) * 32;
  f16* Bl1 = Bs + ((w + 4) * 16) * 32;

  for (int k0 = 0; k0 < K; k0 += 32) {
    __syncthreads();
    gl_lds16(Ag0 + k0, Al0);
    gl_lds16(Ag1 + k0, Al1);
    gl_lds16(Bg0 + k0, Bl0);
    gl_lds16(Bg1 + k0, Bl1);
    __syncthreads();
    f16x8 af[4], bf[4];
#pragma unroll
    for (int fm = 0; fm < 4; ++fm)
      af[fm] = *(const f16x8*)&As[(wm * 64 + fm * 16 + ln) * 32 + quad * 8];
#pragma unroll
    for (int fn = 0; fn < 4; ++fn)
      bf[fn] = *(const f16x8*)&Bs[(wn * 64 + fn * 16 + ln) * 32 + quad * 8];
#pragma unroll
    for (int fm = 0; fm < 4; ++fm)
#pragma unroll
      for (int fn = 0; fn < 4; ++fn)
        acc[fm][fn] = __builtin_amdgcn_mfma_f32_16x16x32_f16(af[fm], bf[fn], acc[fm][fn], 0, 0, 0);
  }
}

// ---------------------------------------------------------------------------
// QKV GEMM + fused epilogue (unchanged from R3):
//   q -> L2-norm -> qb[B,H,N,64]; k -> L2-norm * 0.125*log2e*s[n] -> kb;
//   v -> fp16 transposed -> vt[B,H,64,N]
// ---------------------------------------------------------------------------
__global__ __launch_bounds__(256) void gemm_qkv(const f16* __restrict__ A,
                                                const f16* __restrict__ B,
                                                const float* __restrict__ score,
                                                f16* __restrict__ qb,
                                                f16* __restrict__ kb,
                                                f16* __restrict__ vt) {
  __shared__ __align__(16) union {
    struct { f16 As[128 * 32]; f16 Bs[128 * 32]; } s;
    f16 vtx[4][64][72];
  } sm;
  f32x4 acc[4][4];
#pragma unroll
  for (int i = 0; i < 4; ++i)
#pragma unroll
    for (int j = 0; j < 4; ++j) acc[i][j] = (f32x4){0.f, 0.f, 0.f, 0.f};

  const int bm = blockIdx.y * 128, bn = blockIdx.x * 128;
  gemm_mainloop(A, B, C_DIM, bm, bn, sm.s.As, sm.s.Bs, acc);

  const int tid = threadIdx.x;
  const int w = tid >> 6, lane = tid & 63;
  const int wm = w >> 1, wn = w & 1;
  const int ln = lane & 15, quad = lane >> 4;
  const int col0 = bn + wn * 64;
  const int mode = col0 >> 10;
  const int h    = (col0 >> 6) & 15;

  if (mode <= 1) {
    f16* dst = mode ? kb : qb;
#pragma unroll
    for (int fm = 0; fm < 4; ++fm) {
#pragma unroll
      for (int r = 0; r < 4; ++r) {
        const int m = bm + wm * 64 + fm * 16 + quad * 4 + r;
        const int b = m >> 11, n = m & (N_TOK - 1);
        float ss = acc[fm][0][r] * acc[fm][0][r] + acc[fm][1][r] * acc[fm][1][r]
                 + acc[fm][2][r] * acc[fm][2][r] + acc[fm][3][r] * acc[fm][3][r];
        ss += __shfl_xor(ss, 1, 64);
        ss += __shfl_xor(ss, 2, 64);
        ss += __shfl_xor(ss, 4, 64);
        ss += __shfl_xor(ss, 8, 64);
        float sc = 1.0f / (sqrtf(ss) + 1e-8f);
        if (mode) sc *= 0.125f * LOG2E * score[n];
        f16* drow = dst + (((size_t)(b * H_DIM + h) * N_TOK + n) << 6);
#pragma unroll
        for (int fn = 0; fn < 4; ++fn)
          drow[fn * 16 + ln] = (f16)(acc[fm][fn][r] * sc);
      }
    }
  } else {
    __syncthreads();
#pragma unroll
    for (int fm = 0; fm < 4; ++fm)
#pragma unroll
      for (int fn = 0; fn < 4; ++fn)
#pragma unroll
        for (int r = 0; r < 4; ++r)
          sm.vtx[w][fn * 16 + ln][fm * 16 + quad * 4 + r] = (f16)acc[fm][fn][r];
    const int m0 = bm + wm * 64;
    const int b = m0 >> 11, n0 = m0 & (N_TOK - 1);
    const int dg = lane >> 3;
    const int t8 = (lane & 7) << 3;
#pragma unroll
    for (int g = 0; g < 8; ++g) {
      const int d = g * 8 + dg;
      f16* drow = vt + (((size_t)(b * H_DIM + h) * HD + d) * N_TOK + n0 + t8);
      *(uint4*)drow = *(const uint4*)&sm.vtx[w][d][t8];
    }
  }
}

// ---------------------------------------------------------------------------
// Proj GEMM (unchanged)
// ---------------------------------------------------------------------------
__global__ __launch_bounds__(256) void gemm_proj(const f16* __restrict__ A,
                                                 const f16* __restrict__ B,
                                                 const float* __restrict__ bias,
                                                 float* __restrict__ out) {
  __shared__ __align__(16) struct { f16 As[128 * 32]; f16 Bs[128 * 32]; } sm;
  f32x4 acc[4][4];
#pragma unroll
  for (int i = 0; i < 4; ++i)
#pragma unroll
    for (int j = 0; j < 4; ++j) acc[i][j] = (f32x4){0.f, 0.f, 0.f, 0.f};

  const int bm = blockIdx.y * 128, bn = blockIdx.x * 128;
  gemm_mainloop(A, B, C_DIM, bm, bn, sm.As, sm.Bs, acc);

  const int tid = threadIdx.x;
  const int w = tid >> 6, lane = tid & 63;
  const int wm = w >> 1, wn = w & 1;
  const int ln = lane & 15, quad = lane >> 4;
  float bv[4];
#pragma unroll
  for (int fn = 0; fn < 4; ++fn) bv[fn] = bias[bn + wn * 64 + fn * 16 + ln];
#pragma unroll
  for (int fm = 0; fm < 4; ++fm)
#pragma unroll
    for (int r = 0; r < 4; ++r) {
      const int m = bm + wm * 64 + fm * 16 + quad * 4 + r;
#pragma unroll
      for (int fn = 0; fn < 4; ++fn)
        out[(size_t)m * C_DIM + bn + wn * 64 + fn * 16 + ln] = acc[fm][fn][r] + bv[fn];
    }
}

// ---------------------------------------------------------------------------
// MFMA attention v2. Block = 4 waves x 32 q-rows = 128-query tile of one (b,h).
// K/V staged once per 64-key tile, shared by all 128 q rows.
// Row-sum l computed on the MFMA pipe: Vt has a 5th d-tile whose row 64 is
// all-ones (rows 65..79 zero) -> O[g][4] col 0 accumulates sum_k P.
// ---------------------------------------------------------------------------
__global__ __launch_bounds__(256) void attn_mfma(const f16* __restrict__ qb,
                                                 const f16* __restrict__ kb,
                                                 const f16* __restrict__ vt,
                                                 const float* __restrict__ score,
                                                 const int* __restrict__ usem,
                                                 f16* __restrict__ obuf) {
  __shared__ __align__(16) f16 Ks[64][72];
  __shared__ __align__(16) f16 Vt[80][72];     // rows 64..79: ones-row + zeros
  __shared__ __align__(16) f16 Ps[4][32][72];
  __shared__ float sraw[64];

  const int tid  = threadIdx.x;
  const int w    = tid >> 6;
  const int lane = tid & 63;
  const int ln   = lane & 15;
  const int quad = lane >> 4;
  const int q0 = blockIdx.x * 128;
  const int bh = blockIdx.y;
  const int b  = bh >> 4, h = bh & 15;
  const int umask = *usem;
  const int wq = q0 + w * 32;                  // this wave's first q row

  // Q A-frags for the 2 q-groups (held in registers for the whole kernel)
  f16x8 aq[2][2];
#pragma unroll
  for (int g = 0; g < 2; ++g) {
    const f16* qp = qb + ((size_t)bh * N_TOK + wq + g * 16 + ln) * HD + quad * 8;
    aq[g][0] = *(const f16x8*)(qp);
    aq[g][1] = *(const f16x8*)(qp + 32);
  }

  float si[2][4];
#pragma unroll
  for (int g = 0; g < 2; ++g)
#pragma unroll
    for (int r = 0; r < 4; ++r) si[g][r] = score[wq + g * 16 + quad * 4 + r];

  f32x4 O[2][5];
#pragma unroll
  for (int g = 0; g < 2; ++g)
#pragma unroll
    for (int t = 0; t < 5; ++t) O[g][t] = (f32x4){0.f, 0.f, 0.f, 0.f};

  // init Vt rows 64..79: row 64 = 1.0, rows 65..79 = 0
  for (int i = tid; i < 16 * 72; i += 256)
    Vt[64 + i / 72][i % 72] = (f16)((i / 72 == 0) ? 1.0f : 0.0f);

  const int sr = tid >> 2, sc = (tid & 3) << 4;
  const f16* kbase = kb + ((size_t)bh * N_TOK + sr) * HD + sc;
  const f16* vbase = vt + ((size_t)bh * HD + sr) * N_TOK + sc;

  for (int k0 = 0; k0 < N_TOK; k0 += 64) {
    __syncthreads();
    *(float4*)&Ks[sr][sc]     = *(const float4*)(kbase + (size_t)k0 * HD);
    *(float4*)&Ks[sr][sc + 8] = *(const float4*)(kbase + (size_t)k0 * HD + 8);
    *(float4*)&Vt[sr][sc]     = *(const float4*)(vbase + k0);
    *(float4*)&Vt[sr][sc + 8] = *(const float4*)(vbase + k0 + 8);
    if (tid < 64) sraw[tid] = score[k0 + tid];
    __syncthreads();

    // ---- K B-frags (shared by both q-groups) ----
    f16x8 kf[4][2];
#pragma unroll
    for (int t = 0; t < 4; ++t) {
      kf[t][0] = *(const f16x8*)&Ks[t * 16 + ln][quad * 8];
      kf[t][1] = *(const f16x8*)&Ks[t * 16 + ln][32 + quad * 8];
    }

    // ---- S = Q K''^T, softmax terms, P -> LDS ----
#pragma unroll
    for (int g = 0; g < 2; ++g) {
      f32x4 S[4];
#pragma unroll
      for (int t = 0; t < 4; ++t) {
        f32x4 c = (f32x4){0.f, 0.f, 0.f, 0.f};
        c = __builtin_amdgcn_mfma_f32_16x16x32_f16(aq[g][0], kf[t][0], c, 0, 0, 0);
        c = __builtin_amdgcn_mfma_f32_16x16x32_f16(aq[g][1], kf[t][1], c, 0, 0, 0);
        S[t] = c;
      }
#pragma unroll
      for (int t = 0; t < 4; ++t) {
        const float sjr = sraw[t * 16 + ln];
#pragma unroll
        for (int r = 0; r < 4; ++r) {
          float val = S[t][r];
          if (umask && !(sjr > si[g][r] - 0.1f)) val = 0.f;
          Ps[w][g * 16 + quad * 4 + r][t * 16 + ln] = (f16)exp2f(val);
        }
      }
    }

    // ---- O += P V  (t2=4 is the ones-tile -> row-sum l in col 0) ----
    f16x8 ap[2][2];
#pragma unroll
    for (int g = 0; g < 2; ++g) {
      ap[g][0] = *(const f16x8*)&Ps[w][g * 16 + ln][quad * 8];
      ap[g][1] = *(const f16x8*)&Ps[w][g * 16 + ln][32 + quad * 8];
    }
#pragma unroll
    for (int t2 = 0; t2 < 5; ++t2) {
      const f16x8 bv0 = *(const f16x8*)&Vt[t2 * 16 + ln][quad * 8];
      const f16x8 bv1 = *(const f16x8*)&Vt[t2 * 16 + ln][32 + quad * 8];
#pragma unroll
      for (int g = 0; g < 2; ++g) {
        O[g][t2] = __builtin_amdgcn_mfma_f32_16x16x32_f16(ap[g][0], bv0, O[g][t2], 0, 0, 0);
        O[g][t2] = __builtin_amdgcn_mfma_f32_16x16x32_f16(ap[g][1], bv1, O[g][t2], 0, 0, 0);
      }
    }
  }

  // ---- epilogue: l lives in O[g][4][r] at ln==0 lanes; broadcast in-quad ----
#pragma unroll
  for (int g = 0; g < 2; ++g)
#pragma unroll
    for (int r = 0; r < 4; ++r) {
      const float l = __shfl(O[g][4][r], lane & 48, 64);
      const float inv = 1.0f / l;
      const size_t row = (size_t)(b * N_TOK + q0 + w * 32 + g * 16 + quad * 4 + r);
#pragma unroll
      for (int t2 = 0; t2 < 4; ++t2)
        obuf[row * C_DIM + h * HD + t2 * 16 + ln] = (f16)(O[g][t2][r] * inv);
    }
}

// ---------------------------------------------------------------------------
extern "C" void kernel_launch(void* const* d_in, const int* in_sizes, int n_in,
                              void* d_out, int out_size, void* d_ws, size_t ws_size,
                              hipStream_t stream) {
  const float* x      = (const float*)d_in[0];
  const float* score  = (const float*)d_in[1];
  const float* qkv_w  = (const float*)d_in[2];
  const float* proj_w = (const float*)d_in[3];
  const float* proj_b = (const float*)d_in[4];
  const int*   usem   = (const int*)d_in[5];
  float* out = (float*)d_out;

  f16* xh   = (f16*)d_ws;
  f16* wh   = xh  + (size_t)M_TOK * C_DIM;
  f16* pwh  = wh  + (size_t)3 * C_DIM * C_DIM;
  f16* qb   = pwh + (size_t)C_DIM * C_DIM;
  f16* kb   = qb  + (size_t)M_TOK * C_DIM;
  f16* vt   = kb  + (size_t)M_TOK * C_DIM;
  f16* obuf = vt  + (size_t)M_TOK * C_DIM;

  cvt_all<<<(CVT_X4 + CVT_W4 + CVT_P4) / 256, 256, 0, stream>>>(x, qkv_w, proj_w, xh, wh, pwh);
  {
    dim3 grid(3 * C_DIM / 128, M_TOK / 128);
    gemm_qkv<<<grid, 256, 0, stream>>>(xh, wh, score, qb, kb, vt);
  }
  {
    dim3 grid(N_TOK / 128, 2 * H_DIM);
    attn_mfma<<<grid, 256, 0, stream>>>(qb, kb, vt, score, usem, obuf);
  }
  {
    dim3 grid(C_DIM / 128, M_TOK / 128);
    gemm_proj<<<grid, 256, 0, stream>>>(obuf, pwh, proj_b, out);
  }
}